// Round 1
// 544.157 us; speedup vs baseline: 1.0182x; 1.0182x over previous
//
#include <hip/hip_runtime.h>
#include <cmath>

// ---------------------------------------------------------------------------
// Gemma4 audio attention, MI355X bf16-MFMA pipeline.
// B=2 S=8192 HID=1024 H=8 D=128 CHUNK=128 PAST=127 FUT=128 CTX=383 POS=384
// R6: qkv GEMM rebuilt on the verified 256x256/8-phase template
//     (T1 XCD swizzle + T2 st_16x32 LDS swizzle via pre-swizzled global src +
//      T3/T4 counted-vmcnt 4-phase-per-K-tile pipeline + T5 setprio).
//     512 threads, 8 waves (2Mx4N), BK=64, 128 KiB LDS double buffer,
//     1 block/CU. Stage schedule: A 1 tile ahead, B 2 tiles ahead,
//     steady-state s_waitcnt vmcnt(4) once per K-tile (never 0 in loop).
//     Everything else (bd/rel/attn/post) unchanged from R5.
// ---------------------------------------------------------------------------

using bf16x8 = __attribute__((ext_vector_type(8))) short;
using f32x4  = __attribute__((ext_vector_type(4))) float;
using s16x4  = __attribute__((ext_vector_type(4))) short;

__device__ __forceinline__ short f2bf(float f) {
  unsigned u = __float_as_uint(f);
  u = (u + 0x7FFF + ((u >> 16) & 1)) >> 16;   // RNE
  return (short)u;
}
__device__ __forceinline__ float bf2f(unsigned short s) {
  return __uint_as_float(((unsigned)s) << 16);
}

// async global->LDS, 16B per lane. LDS dest must be wave-uniform base + lane*16.
__device__ __forceinline__ void gl16(void* lds, const void* gptr) {
  __builtin_amdgcn_global_load_lds(
      (const __attribute__((address_space(1))) unsigned int*)gptr,
      (__attribute__((address_space(3))) unsigned int*)lds, 16, 0, 0);
}

// ---------------------------------------------------------------------------
// elementwise fp32 -> bf16
__global__ void cvt_bf16_k(const float* __restrict__ in, short* __restrict__ out, int n) {
  int i = (blockIdx.x * 256 + threadIdx.x) * 4;
  if (i + 3 < n) {
    float4 v = *(const float4*)&in[i];
    s16x4 o;
    o[0] = f2bf(v.x); o[1] = f2bf(v.y); o[2] = f2bf(v.z); o[3] = f2bf(v.w);
    *(s16x4*)&out[i] = o;
  }
}

// W (1024x1024 f32, [k][n]) -> Wt (bf16, [n][k])
__global__ void wtrans_k(const float* __restrict__ W, short* __restrict__ Wt) {
  __shared__ float T[64 * 65];
  const int tid = threadIdx.x;
  const int bx = blockIdx.x, by = blockIdx.y; // bx: n-tile, by: k-tile
#pragma unroll
  for (int it = 0; it < 4; ++it) {
    int ci = it * 256 + tid;
    int k = ci >> 4, n4 = (ci & 15) * 4;
    float4 v = *(const float4*)&W[(size_t)(by * 64 + k) * 1024 + bx * 64 + n4];
    T[k * 65 + n4 + 0] = v.x;
    T[k * 65 + n4 + 1] = v.y;
    T[k * 65 + n4 + 2] = v.z;
    T[k * 65 + n4 + 3] = v.w;
  }
  __syncthreads();
#pragma unroll
  for (int it = 0; it < 2; ++it) {
    int co = it * 256 + tid;
    int nn = co >> 3, k8 = (co & 7) * 8;
    bf16x8 o;
#pragma unroll
    for (int jj = 0; jj < 8; ++jj) o[jj] = f2bf(T[(k8 + jj) * 65 + nn]);
    *(bf16x8*)&Wt[(size_t)(bx * 64 + nn) * 1024 + by * 64 + k8] = o;
  }
}

// qscale[d] = (1/sqrt(128))/ln2 * softplus(pds[d])
__global__ void qscale_k(const float* __restrict__ pds, float* __restrict__ qs, double qsb) {
  int d = threadIdx.x;
  double x = (double)pds[d];
  qs[d] = (float)(qsb * log1p(exp(x)));
}

// zero vpadT pad columns: keys [0,127) and [8319,8448)
__global__ void vpadzero_k(short* __restrict__ vpadT) {
  int row = blockIdx.x;                 // (b*8+h)*128 + d   (2048 rows)
  int t = threadIdx.x;                  // 256
  int key = (t < 127) ? t : (8192 + t); // 0..126 and 8319..8447
  vpadT[(size_t)row * 8448 + key] = 0;
}

// ---------------------------------------------------------------------------
// R6 fused QKV GEMM: 256x256 tile, BK=64, 8-phase pipeline.
// LDS half-tile layout: linear dest (gl16) holding the st_16x32-swizzled tile:
//   LDS[row*128B + cb] = G[row, cb ^ ((row>>2)&1)<<5]   (involution)
// so reads apply the same XOR on the column-byte.

__device__ __forceinline__ void stage_half(short* ldsb, const short* gbase, int tid) {
#pragma unroll
  for (int it = 0; it < 2; ++it) {
    int L = (it * 512 + tid) * 16;                 // byte offset in 16 KiB half
    int r = L >> 7;                                // row (0..127)
    int cb = (L & 127) ^ (((L >> 9) & 1) << 5);    // inverse-swizzled col byte
    gl16((char*)ldsb + L, gbase + (size_t)r * 1024 + (cb >> 1));
  }
}

__device__ __forceinline__ bf16x8 frag_ld(const short* hb, int row, int ks, int q4) {
  int cb = (ks * 64 + q4 * 16) ^ (((row >> 2) & 1) << 5);
  return *(const bf16x8*)((const char*)hb + row * 128 + cb);
}

__global__ __launch_bounds__(512, 2)
void qkv256_k(const short* __restrict__ A, const short* __restrict__ Bt3,
              short* __restrict__ q_bf, short* __restrict__ kpad,
              short* __restrict__ vpadT,
              const float* __restrict__ qsc, float kscale) {
  // [buf(2)][half(4): A0,A1,B0,B1][128*64 bf16] = 128 KiB
  __shared__ __align__(16) short lds[65536];

  const int tid = threadIdx.x;
  const int lane = tid & 63, wid = tid >> 6;
  const int q4 = lane >> 4, l16 = lane & 15;
  const int wr = wid >> 2, wc = wid & 3;          // 2 M-waves x 4 N-waves

  // XCD-pinned swizzle: 768 blocks = 8 XCD x (8 Mtiles x 12 Ntiles)
  const int id = blockIdx.x;
  const int xcd = id & 7, local = id >> 3;
  const int mm = xcd * 8 + local / 12, nn = local % 12;
  const int m0 = mm * 256, n0 = nn * 256;

  const short* Abase = A + (size_t)m0 * 1024;     // row-major [16384][1024]
  const short* Bbase = Bt3 + (size_t)n0 * 1024;   // 3 weights contiguous, [n][k]

  const f32x4 z4 = {0.f, 0.f, 0.f, 0.f};
  f32x4 acc[8][4];
#pragma unroll
  for (int i = 0; i < 8; ++i)
#pragma unroll
    for (int j = 0; j < 4; ++j) acc[i][j] = z4;

  // ---- prologue: t0 {A0,A1,B0,B1}, t1 {B0,B1}; retire t0, keep t1B in flight
  stage_half(lds + 0 * 32768 + 0 * 8192, Abase, tid);
  stage_half(lds + 0 * 32768 + 1 * 8192, Abase + 128 * 1024, tid);
  stage_half(lds + 0 * 32768 + 2 * 8192, Bbase, tid);
  stage_half(lds + 0 * 32768 + 3 * 8192, Bbase + 128 * 1024, tid);
  stage_half(lds + 1 * 32768 + 2 * 8192, Bbase + 64, tid);
  stage_half(lds + 1 * 32768 + 3 * 8192, Bbase + 128 * 1024 + 64, tid);
  asm volatile("s_waitcnt vmcnt(4)" ::: "memory");
  __builtin_amdgcn_s_barrier();

  for (int kt = 0; kt < 16; ++kt) {
    const int buf = kt & 1;
    const short* Acur = lds + buf * 32768 + wr * 8192;              // this wave's A half
    const short* Bcur = lds + buf * 32768 + (2 + (wc >> 1)) * 8192; // this wave's B half
    const int brow0 = (wc & 1) * 64;

    bf16x8 bfr[4][2];   // B frags held in regs across all 4 phases

    // ---- phase 0: B frags (8 reads) + A quadrant 0 (4 reads); stage (kt+1)A0
    {
#pragma unroll
      for (int j = 0; j < 4; ++j)
#pragma unroll
        for (int ks = 0; ks < 2; ++ks)
          bfr[j][ks] = frag_ld(Bcur, brow0 + j * 16 + l16, ks, q4);
      bf16x8 afr[2][2];
#pragma unroll
      for (int m2 = 0; m2 < 2; ++m2)
#pragma unroll
        for (int ks = 0; ks < 2; ++ks)
          afr[m2][ks] = frag_ld(Acur, m2 * 16 + l16, ks, q4);
      if (kt < 15)
        stage_half(lds + (buf ^ 1) * 32768 + 0 * 8192, Abase + (size_t)(kt + 1) * 64, tid);
      asm volatile("s_waitcnt lgkmcnt(8)" ::: "memory");
      __builtin_amdgcn_s_barrier();
      asm volatile("s_waitcnt lgkmcnt(0)" ::: "memory");
      __builtin_amdgcn_s_setprio(1);
#pragma unroll
      for (int ks = 0; ks < 2; ++ks)
#pragma unroll
        for (int m2 = 0; m2 < 2; ++m2)
#pragma unroll
          for (int j = 0; j < 4; ++j)
            acc[m2][j] = __builtin_amdgcn_mfma_f32_16x16x32_bf16(
                afr[m2][ks], bfr[j][ks], acc[m2][j], 0, 0, 0);
      __builtin_amdgcn_s_setprio(0);
      __builtin_amdgcn_s_barrier();
    }

    // ---- phases 1..3: A quadrant p (4 reads); stage {(kt+1)A1,(kt+2)B0,(kt+2)B1}
#pragma unroll
    for (int p = 1; p < 4; ++p) {
      bf16x8 afr[2][2];
#pragma unroll
      for (int m2 = 0; m2 < 2; ++m2)
#pragma unroll
        for (int ks = 0; ks < 2; ++ks)
          afr[m2][ks] = frag_ld(Acur, (p * 2 + m2) * 16 + l16, ks, q4);
      if (p == 1) {
        if (kt < 15)
          stage_half(lds + (buf ^ 1) * 32768 + 1 * 8192,
                     Abase + 128 * 1024 + (size_t)(kt + 1) * 64, tid);
      } else if (p == 2) {
        if (kt < 14)
          stage_half(lds + buf * 32768 + 2 * 8192, Bbase + (size_t)(kt + 2) * 64, tid);
      } else {
        if (kt < 14)
          stage_half(lds + buf * 32768 + 3 * 8192,
                     Bbase + 128 * 1024 + (size_t)(kt + 2) * 64, tid);
      }
      __builtin_amdgcn_s_barrier();
      asm volatile("s_waitcnt lgkmcnt(0)" ::: "memory");
      __builtin_amdgcn_s_setprio(1);
#pragma unroll
      for (int ks = 0; ks < 2; ++ks)
#pragma unroll
        for (int m2 = 0; m2 < 2; ++m2)
#pragma unroll
          for (int j = 0; j < 4; ++j)
            acc[p * 2 + m2][j] = __builtin_amdgcn_mfma_f32_16x16x32_bf16(
                afr[m2][ks], bfr[j][ks], acc[p * 2 + m2][j], 0, 0, 0);
      __builtin_amdgcn_s_setprio(0);
      if (p == 3) {
        // counted wait, once per K-tile; drain fully only at the pipeline tail
        if (kt < 14) asm volatile("s_waitcnt vmcnt(4)" ::: "memory");
        else         asm volatile("s_waitcnt vmcnt(0)" ::: "memory");
      }
      __builtin_amdgcn_s_barrier();
    }
  }

  // ---- epilogue -----------------------------------------------------------
  const int w = n0 >> 10;          // 0=Q,1=K,2=V
  const int cw = n0 & 1023;        // col offset within this weight
  const int b = m0 >> 13;          // uniform per block
  const int s_base = (m0 & 8191) + wr * 128;

  if (w == 0) {                    // Q -> q_bf[(b*64+n)*8+h][c][d] * qscale[d]
    float qsv[4];
#pragma unroll
    for (int j = 0; j < 4; ++j) qsv[j] = qsc[(cw + wc * 64 + j * 16 + l16) & 127];
#pragma unroll
    for (int m = 0; m < 8; ++m)
#pragma unroll
      for (int j = 0; j < 4; ++j)
#pragma unroll
        for (int rg = 0; rg < 4; ++rg) {
          int s = s_base + m * 16 + q4 * 4 + rg;
          int col = cw + wc * 64 + j * 16 + l16;
          int h = col >> 7, d = col & 127;
          int n = s >> 7, c = s & 127;
          q_bf[((size_t)(((b * 64 + n) * 8 + h) * 128 + c)) * 128 + d] =
              f2bf(acc[m][j][rg] * qsv[j]);
        }
  } else if (w == 1) {             // K -> kpad[b][h][127+s][d] * kscale
#pragma unroll
    for (int m = 0; m < 8; ++m)
#pragma unroll
      for (int j = 0; j < 4; ++j)
#pragma unroll
        for (int rg = 0; rg < 4; ++rg) {
          int s = s_base + m * 16 + q4 * 4 + rg;
          int col = cw + wc * 64 + j * 16 + l16;
          int h = col >> 7, d = col & 127;
          kpad[((size_t)(b * 8 + h) * 8448 + 127 + s) * 128 + d] =
              f2bf(acc[m][j][rg] * kscale);
        }
  } else {                         // V -> vpadT[(b*8+h)*128+d][127+s], LDS transpose
    short* T = lds;                // reuse main-loop LDS (all staged data consumed)
#pragma unroll
    for (int hh = 0; hh < 2; ++hh) {
      __syncthreads();
      if ((wc >> 1) == hh) {
#pragma unroll
        for (int m = 0; m < 8; ++m)
#pragma unroll
          for (int j = 0; j < 4; ++j)
#pragma unroll
            for (int rg = 0; rg < 4; ++rg) {
              int sl = wr * 128 + m * 16 + q4 * 4 + rg;  // 0..255
              int dl = (wc & 1) * 64 + j * 16 + l16;     // 0..127
              T[dl * 264 + sl] = f2bf(acc[m][j][rg]);
            }
      }
      __syncthreads();
      const int h = (cw >> 7) + hh;
#pragma unroll
      for (int it = 0; it < 8; ++it) {
        int co = it * 512 + tid;
        int dd = co >> 5, s8 = (co & 31) * 8;
        *(bf16x8*)&vpadT[((size_t)(b * 8 + h) * 128 + dd) * 8448 + 127 + (m0 & 8191) + s8] =
            *(const bf16x8*)&T[dd * 264 + s8];
      }
    }
  }
}

// ---------------------------------------------------------------------------
// Post GEMM (f32 out), XCD-pinned swizzle (unchanged).
__global__ __launch_bounds__(256, 3)
void post_gemm_k(const short* __restrict__ A, const short* __restrict__ Bt,
                 float* __restrict__ outf) {
  __shared__ __align__(16) short As[128 * 32];
  __shared__ __align__(16) short Bs[128 * 32];

  const int tid = threadIdx.x;
  const int lane = tid & 63, wid = tid >> 6;
  const int q4 = lane >> 4, l16 = lane & 15;
  const int wr = wid >> 1, wc = wid & 1;

  const int id = blockIdx.x;
  const int xcd = id & 7, local = id >> 3;     // local in [0,128)
  const int mm = local >> 3, nn = local & 7;
  const int m0 = (xcd * 16 + mm) * 128, n0 = nn * 128;

  const f32x4 z4 = {0.f, 0.f, 0.f, 0.f};
  f32x4 acc[4][4];
#pragma unroll
  for (int i = 0; i < 4; ++i)
#pragma unroll
    for (int j = 0; j < 4; ++j) acc[i][j] = z4;

  const int r0 = tid >> 2, s0_ = (tid & 3) * 8;

  for (int kk = 0; kk < 1024; kk += 32) {
    __syncthreads();
    gl16(&As[tid * 8],         A  + (size_t)(m0 + r0) * 1024 + kk + s0_);
    gl16(&Bs[tid * 8],         Bt + (size_t)(n0 + r0) * 1024 + kk + s0_);
    gl16(&As[(256 + tid) * 8], A  + (size_t)(m0 + 64 + r0) * 1024 + kk + s0_);
    gl16(&Bs[(256 + tid) * 8], Bt + (size_t)(n0 + 64 + r0) * 1024 + kk + s0_);
    __syncthreads();
    bf16x8 af[4], bfv[4];
#pragma unroll
    for (int i = 0; i < 4; ++i)
      af[i] = *(const bf16x8*)&As[(wr * 64 + i * 16 + l16) * 32 + q4 * 8];
#pragma unroll
    for (int j = 0; j < 4; ++j)
      bfv[j] = *(const bf16x8*)&Bs[(wc * 64 + j * 16 + l16) * 32 + q4 * 8];
#pragma unroll
    for (int i = 0; i < 4; ++i)
#pragma unroll
      for (int j = 0; j < 4; ++j)
        acc[i][j] = __builtin_amdgcn_mfma_f32_16x16x32_bf16(af[i], bfv[j], acc[i][j], 0, 0, 0);
  }

#pragma unroll
  for (int i = 0; i < 4; ++i)
#pragma unroll
    for (int j = 0; j < 4; ++j)
#pragma unroll
      for (int rg = 0; rg < 4; ++rg) {
        const int row = m0 + wr * 64 + i * 16 + q4 * 4 + rg;
        const int col = n0 + wc * 64 + j * 16 + l16;
        outf[(size_t)row * 1024 + col] = acc[i][j][rg];
      }
}

// ---------------------------------------------------------------------------
// REL GEMM: C = pos_bf(384x1024) @ Wrel_t^T -> relk[h][p][d]. grid (3,8).
__global__ __launch_bounds__(256, 2)
void rel_gemm_k(const short* __restrict__ A, const short* __restrict__ Bt,
                short* __restrict__ relk) {
  __shared__ __align__(16) short As[128 * 32];
  __shared__ __align__(16) short Bs[128 * 32];

  const int tid = threadIdx.x;
  const int lane = tid & 63, wid = tid >> 6;
  const int q4 = lane >> 4, l16 = lane & 15;
  const int wr = wid >> 1, wc = wid & 1;
  const int m0 = blockIdx.x * 128, n0 = blockIdx.y * 128;

  const f32x4 z4 = {0.f, 0.f, 0.f, 0.f};
  f32x4 acc[4][4];
#pragma unroll
  for (int i = 0; i < 4; ++i)
#pragma unroll
    for (int j = 0; j < 4; ++j) acc[i][j] = z4;

  const int r0 = tid >> 2, s0_ = (tid & 3) * 8;
  for (int kk = 0; kk < 1024; kk += 32) {
    __syncthreads();
    gl16(&As[tid * 8],         A  + (size_t)(m0 + r0) * 1024 + kk + s0_);
    gl16(&Bs[tid * 8],         Bt + (size_t)(n0 + r0) * 1024 + kk + s0_);
    gl16(&As[(256 + tid) * 8], A  + (size_t)(m0 + 64 + r0) * 1024 + kk + s0_);
    gl16(&Bs[(256 + tid) * 8], Bt + (size_t)(n0 + 64 + r0) * 1024 + kk + s0_);
    __syncthreads();
    bf16x8 af[4], bfv[4];
#pragma unroll
    for (int i = 0; i < 4; ++i)
      af[i] = *(const bf16x8*)&As[(wr * 64 + i * 16 + l16) * 32 + q4 * 8];
#pragma unroll
    for (int j = 0; j < 4; ++j)
      bfv[j] = *(const bf16x8*)&Bs[(wc * 64 + j * 16 + l16) * 32 + q4 * 8];
#pragma unroll
    for (int i = 0; i < 4; ++i)
#pragma unroll
      for (int j = 0; j < 4; ++j)
        acc[i][j] = __builtin_amdgcn_mfma_f32_16x16x32_bf16(af[i], bfv[j], acc[i][j], 0, 0, 0);
  }

#pragma unroll
  for (int i = 0; i < 4; ++i)
#pragma unroll
    for (int j = 0; j < 4; ++j)
#pragma unroll
      for (int rg = 0; rg < 4; ++rg) {
        const int row = m0 + wr * 64 + i * 16 + q4 * 4 + rg;
        const int col = n0 + wc * 64 + j * 16 + l16;
        int h = col >> 7, d = col & 127;
        relk[(size_t)(h * 384 + row) * 128 + d] = f2bf(acc[i][j][rg]);
      }
}

// ---------------------------------------------------------------------------
// bdo = q_tile(128x128) @ relk[h](384x128)^T, rel-shift applied in epilogue,
// stored in MFMA-fragment order for attn_k (unchanged from R4).
__global__ __launch_bounds__(256, 2)
void bd_gemm_k(const short* __restrict__ qb_b, const short* __restrict__ relk,
               short* __restrict__ bds) {
  __shared__ __align__(16) short As[128 * 32];
  __shared__ __align__(16) short Bs[128 * 32];
  const int tid = threadIdx.x;
  const int lane = tid & 63, wid = tid >> 6;
  const int q4 = lane >> 4, l16 = lane & 15;
  const int wr = wid >> 1, wc = wid & 1;
  const int p0 = blockIdx.x * 128;
  const int nh = blockIdx.y;          // n*8 + h  (within b)
  const int h = nh & 7;
  const short* A = qb_b + (size_t)nh * 16384;
  const short* Bt = relk + (size_t)h * (384 * 128);
  short* bdo = bds + (size_t)nh * 49152;

  const f32x4 z4 = {0.f, 0.f, 0.f, 0.f};
  f32x4 acc[4][4];
#pragma unroll
  for (int i = 0; i < 4; ++i)
#pragma unroll
    for (int j = 0; j < 4; ++j) acc[i][j] = z4;

  const int r0 = tid >> 2, s0_ = (tid & 3) * 8;
  for (int kk = 0; kk < 128; kk += 32) {
    __syncthreads();
    gl16(&As[tid * 8],         A  + (size_t)r0 * 128 + kk + s0_);
    gl16(&Bs[tid * 8],         Bt + (size_t)(p0 + r0) * 128 + kk + s0_);
    gl16(&As[(256 + tid) * 8], A  + (size_t)(64 + r0) * 128 + kk + s0_);
    gl16(&Bs[(256 + tid) * 8], Bt + (size_t)(p0 + 64 + r0) * 128 + kk + s0_);
    __syncthreads();
    bf16x8 af[4], bfv[4];
#pragma unroll
    for (int i = 0; i < 4; ++i)
      af[i] = *(const bf16x8*)&As[(wr * 64 + i * 16 + l16) * 32 + q4 * 8];
#pragma unroll
    for (int j = 0; j < 4; ++j)
      bfv[j] = *(const bf16x8*)&Bs[(wc * 64 + j * 16 + l16) * 32 + q4 * 8];
#pragma unroll
    for (int i = 0; i < 4; ++i)
#pragma unroll
      for (int j = 0; j < 4; ++j)
        acc[i][j] = __builtin_amdgcn_mfma_f32_16x16x32_bf16(af[i], bfv[j], acc[i][j], 0, 0, 0);
  }

  // rel-shift: (r,p) -> (c,k): flat r*384+p == c*383+k, drop c >= 128
#pragma unroll
  for (int i = 0; i < 4; ++i)
#pragma unroll
    for (int j = 0; j < 4; ++j)
#pragma unroll
      for (int rg = 0; rg < 4; ++rg) {
        int r = wr * 64 + i * 16 + q4 * 4 + rg;
        int p = p0 + wc * 64 + j * 16 + l16;
        int t = r + p;
        int c = (t < 383) ? r : (r + 1);
        int k = (t < 383) ? t : (t - 383);
        if (c < 128) {
          int tt = k >> 7, jj = (k >> 4) & 7, ll = k & 15;
          int wa = c >> 5, ia = (c >> 4) & 1, qa = (c >> 2) & 3, ra = c & 3;
          bdo[((((size_t)tt * 8 + jj) * 256) + wa * 64 + qa * 16 + ll) * 8 + ia * 4 + ra] =
              f2bf(acc[i][j][rg]);
        }
      }
}

// ---------------------------------------------------------------------------
// fused local attention, 64-query-row blocks: one WG per (n,h,qh) for fixed b.
// grid 1024. LDS 50.2 KB -> 3 blocks/CU.
__global__ __launch_bounds__(256, 3)
void attn_k(const short* __restrict__ qb_b, const short* __restrict__ kpad,
            const short* __restrict__ vpadT, const short* __restrict__ bds,
            short* __restrict__ attnout, int b) {
  __shared__ __align__(16) short Ks[4 * 128 * 32]; // slabs [dc][row][32], reused Q->K->V
  __shared__ __align__(16) short Ps[64 * 136];     // 64-row P tile, padded stride

  const int tid = threadIdx.x;
  const int lane = tid & 63, wid = tid >> 6;
  const int q4 = lane >> 4, l16 = lane & 15;
  const int bx = blockIdx.x;          // (n*8 + h)*2 + qh
  const int qh = bx & 1, nh = bx >> 1;
  const int n = nh >> 3, h = nh & 7;

  const short* qtile = qb_b + (size_t)nh * 16384 + qh * 64 * 128;
  const short* kbase = kpad + ((size_t)(b * 8 + h) * 8448 + n * 128) * 128;
  const short* vtb = vpadT + (size_t)(b * 8 + h) * 128 * 8448 + n * 128;
  const short* bdb = bds + (size_t)nh * 49152;

  // stage this half's Q (64x128) into Ks, pull fragments to registers
#pragma unroll
  for (int it = 0; it < 4; ++it) {
    int ci = it * 256 + tid;                     // [0,1024)
    int dc = ci >> 8, rr = (ci >> 2) & 63, sub = (ci & 3) * 8;
    gl16(&Ks[ci * 8], qtile + rr * 128 + dc * 32 + sub);
  }
  __syncthreads();
  bf16x8 qf[4];
#pragma unroll
  for (int dc = 0; dc < 4; ++dc)
    qf[dc] = *(const bf16x8*)&Ks[dc * 2048 + (wid * 16 + l16) * 32 + q4 * 8];

  const f32x4 z4 = {0.f, 0.f, 0.f, 0.f};
  f32x4 acco[8];
#pragma unroll
  for (int j = 0; j < 8; ++j) acco[j] = z4;
  float rsum[4] = {};

  for (int t = 0; t < 3; ++t) {
    __syncthreads();  // (A) Ks/Ps free
#pragma unroll
    for (int it = 0; it < 8; ++it) {  // stage K tile (full 128 keys)
      int ci = it * 256 + tid;
      int dc = ci >> 9, rr = (ci >> 2) & 127, sub = (ci & 3) * 8;
      gl16(&Ks[ci * 8], kbase + (size_t)(t * 128 + rr) * 128 + dc * 32 + sub);
    }

    // bd fragment loads (8B per lane, this wave's ia-half only)
    s16x4 bdv[8];
#pragma unroll
    for (int j = 0; j < 8; ++j)
      bdv[j] = *(const s16x4*)&bdb[((((size_t)t * 8 + j) * 256) +
                 (qh * 2 + (wid >> 1)) * 64 + q4 * 16 + l16) * 8 + (wid & 1) * 4];

    __syncthreads();  // (B) K ready

    // S = Q @ K^T  (16 rows per wave)
    f32x4 accs[8];
#pragma unroll
    for (int j = 0; j < 8; ++j) accs[j] = z4;
#pragma unroll
    for (int dc = 0; dc < 4; ++dc) {
      bf16x8 kf[8];
#pragma unroll
      for (int j = 0; j < 8; ++j)
        kf[j] = *(const bf16x8*)&Ks[dc * 4096 + (j * 16 + l16) * 32 + q4 * 8];
#pragma unroll
      for (int j = 0; j < 8; ++j)
        accs[j] = __builtin_amdgcn_mfma_f32_16x16x32_bf16(qf[dc], kf[j], accs[j], 0, 0, 0);
    }

    // logits: s = ac + bd;  w = exp2(-100*log2e / (exp2(s*2*log2e/50) + 1))
#pragma unroll
    for (int j = 0; j < 8; ++j) {
      const int kg = t * 128 + j * 16 + l16;
#pragma unroll
      for (int rg = 0; rg < 4; ++rg) {
        float sv = accs[j][rg] + bf2f((unsigned short)bdv[j][rg]);
        float tt = exp2f(sv * 0.057707801635558534f);
        float wgt = exp2f(-144.26950408889634f * __fdividef(1.0f, tt + 1.0f));
        wgt = (kg < 383) ? wgt : 0.0f;
        accs[j][rg] = wgt;
        rsum[rg] += wgt;
      }
    }
    __syncthreads();  // (C) all waves done reading Ks (K tile)

    // stage V^T tile into Ks slabs [kc][d][32keys]; write P to Ps
#pragma unroll
    for (int it = 0; it < 8; ++it) {
      int ci = it * 256 + tid;
      int kc = ci >> 9, dd = (ci >> 2) & 127, sub = (ci & 3) * 8;
      gl16(&Ks[ci * 8], vtb + (size_t)dd * 8448 + t * 128 + kc * 32 + sub);
    }
#pragma unroll
    for (int j = 0; j < 8; ++j)
#pragma unroll
      for (int rg = 0; rg < 4; ++rg) {
        int c = wid * 16 + q4 * 4 + rg;
        int kl = j * 16 + l16;
        Ps[c * 136 + kl] = f2bf(accs[j][rg]);
      }
    __syncthreads();  // (D) V + P ready

    // PV over kc = 0..3
#pragma unroll
    for (int kc = 0; kc < 4; ++kc) {
      bf16x8 pf, vf[8];
      pf = *(const bf16x8*)&Ps[(wid * 16 + l16) * 136 + kc * 32 + q4 * 8];
#pragma unroll
      for (int j = 0; j < 8; ++j)
        vf[j] = *(const bf16x8*)&Ks[kc * 4096 + (j * 16 + l16) * 32 + q4 * 8];
#pragma unroll
      for (int j = 0; j < 8; ++j)
        acco[j] = __builtin_amdgcn_mfma_f32_16x16x32_bf16(pf, vf[j], acco[j], 0, 0, 0);
    }
  }

  // row-sum butterfly over the 16-lane group (cols), normalize, write bf16
  float rinv[4];
#pragma unroll
  for (int rg = 0; rg < 4; ++rg) {
    float rs = rsum[rg];
    rs += __shfl_xor(rs, 1);
    rs += __shfl_xor(rs, 2);
    rs += __shfl_xor(rs, 4);
    rs += __shfl_xor(rs, 8);
    rinv[rg] = __fdividef(1.0f, rs);
  }
#pragma unroll
  for (int j = 0; j < 8; ++j)
#pragma unroll
    for (int rg = 0; rg < 4; ++rg) {
      int srow = n * 128 + qh * 64 + wid * 16 + q4 * 4 + rg;
      int col = h * 128 + j * 16 + l16;
      attnout[((size_t)b * 8192 + srow) * 1024 + col] = f2bf(acco[j][rg] * rinv[rg]);
    }
}

// ---------------------------------------------------------------------------
extern "C" void kernel_launch(void* const* d_in, const int* in_sizes, int n_in,
                              void* d_out, int out_size, void* d_ws, size_t ws_size,
                              hipStream_t stream) {
  (void)in_sizes; (void)n_in; (void)out_size; (void)ws_size;
  const float* hs    = (const float*)d_in[0];
  const float* pemb  = (const float*)d_in[1];
  const float* Wq    = (const float*)d_in[2];
  const float* Wk    = (const float*)d_in[3];
  const float* Wv    = (const float*)d_in[4];
  const float* Wrel  = (const float*)d_in[5];
  const float* Wpost = (const float*)d_in[6];
  const float* pds   = (const float*)d_in[7];
  float* out = (float*)d_out;

  char* w = (char*)d_ws;
  auto alloc = [&](size_t bytes) -> char* {
    char* p = w; w += (bytes + 255) & ~(size_t)255; return p;
  };
  short* hs_bf   = (short*)alloc((size_t)16384 * 1024 * 2); // 33.5 MB (attnout aliases later)
  short* pos_bf  = (short*)alloc((size_t)384 * 1024 * 2);
  short* Wq_t    = (short*)alloc((size_t)1024 * 1024 * 2);  // Wq_t/Wk_t/Wv_t contiguous = Bt3
  short* Wk_t    = (short*)alloc((size_t)1024 * 1024 * 2);
  short* Wv_t    = (short*)alloc((size_t)1024 * 1024 * 2);
  short* Wrel_t  = (short*)alloc((size_t)1024 * 1024 * 2);
  short* Wpost_t = (short*)alloc((size_t)1024 * 1024 * 2);
  float* qsc     = (float*)alloc(512);
  short* q_bf    = (short*)alloc((size_t)2 * 64 * 8 * 128 * 128 * 2); // 33.5 MB
  short* kpad    = (short*)alloc((size_t)2 * 8 * 8448 * 128 * 2);     // 34.6 MB
  short* vpadT   = (short*)alloc((size_t)2 * 8 * 128 * 8448 * 2);     // 34.6 MB
  short* relk    = (short*)alloc((size_t)8 * 384 * 128 * 2);
  short* bds     = (short*)alloc((size_t)64 * 8 * 128 * 384 * 2);     // 50.3 MB, per-b (reused)
  short* attnout = hs_bf;  // hs_bf dead after QKV projection; attn starts after
  // total ~199 MB (< 232 MB known-good)

  const float kscale = (float)(log1p(exp(1.0)) / log(2.0));
  const double qsb = (1.0 / sqrt(128.0)) / log(2.0);

  cvt_bf16_k<<<16384, 256, 0, stream>>>(hs, hs_bf, 16384 * 1024);
  cvt_bf16_k<<<384, 256, 0, stream>>>(pemb, pos_bf, 384 * 1024);
  dim3 tg(16, 16);
  wtrans_k<<<tg, 256, 0, stream>>>(Wq, Wq_t);
  wtrans_k<<<tg, 256, 0, stream>>>(Wk, Wk_t);
  wtrans_k<<<tg, 256, 0, stream>>>(Wv, Wv_t);
  wtrans_k<<<tg, 256, 0, stream>>>(Wrel, Wrel_t);
  wtrans_k<<<tg, 256, 0, stream>>>(Wpost, Wpost_t);
  qscale_k<<<1, 128, 0, stream>>>(pds, qsc, qsb);
  hipMemsetAsync(kpad, 0, (size_t)2 * 8 * 8448 * 128 * 2, stream);
  vpadzero_k<<<2048, 256, 0, stream>>>(vpadT);

  qkv256_k<<<768, 512, 0, stream>>>(hs_bf, Wq_t, q_bf, kpad, vpadT, qsc, kscale);
  rel_gemm_k<<<dim3(3, 8), 256, 0, stream>>>(pos_bf, Wrel_t, relk);

  for (int b = 0; b < 2; ++b) {
    const short* qb_b = q_bf + (size_t)b * 64 * 8 * 128 * 128;
    bd_gemm_k<<<dim3(3, 512), 256, 0, stream>>>(qb_b, relk, bds);
    attn_k<<<1024, 256, 0, stream>>>(qb_b, kpad, vpadT, bds, attnout, b);
  }

  post_gemm_k<<<1024, 256, 0, stream>>>(attnout, Wpost_t, out);
}

// Round 2
// 505.230 us; speedup vs baseline: 1.0967x; 1.0770x over previous
//
#include <hip/hip_runtime.h>
#include <cmath>

// ---------------------------------------------------------------------------
// Gemma4 audio attention, MI355X bf16-MFMA pipeline.
// B=2 S=8192 HID=1024 H=8 D=128 CHUNK=128 PAST=127 FUT=128 CTX=383 POS=384
// R7: (1) qkv256 LDS swizzle fixed: 3-bit slot XOR (slot ^= row&7) instead of
//     the half-broken 1-bit XOR -> conflict-free ds_read_b128 (8 words/bank).
//     (2) post_gemm ported to the same 256x256/8-phase template (post256_k),
//     grid 256 = 1 block/CU. Everything else unchanged from R6.
// ---------------------------------------------------------------------------

using bf16x8 = __attribute__((ext_vector_type(8))) short;
using f32x4  = __attribute__((ext_vector_type(4))) float;
using s16x4  = __attribute__((ext_vector_type(4))) short;

__device__ __forceinline__ short f2bf(float f) {
  unsigned u = __float_as_uint(f);
  u = (u + 0x7FFF + ((u >> 16) & 1)) >> 16;   // RNE
  return (short)u;
}
__device__ __forceinline__ float bf2f(unsigned short s) {
  return __uint_as_float(((unsigned)s) << 16);
}

// async global->LDS, 16B per lane. LDS dest must be wave-uniform base + lane*16.
__device__ __forceinline__ void gl16(void* lds, const void* gptr) {
  __builtin_amdgcn_global_load_lds(
      (const __attribute__((address_space(1))) unsigned int*)gptr,
      (__attribute__((address_space(3))) unsigned int*)lds, 16, 0, 0);
}

// ---------------------------------------------------------------------------
// elementwise fp32 -> bf16
__global__ void cvt_bf16_k(const float* __restrict__ in, short* __restrict__ out, int n) {
  int i = (blockIdx.x * 256 + threadIdx.x) * 4;
  if (i + 3 < n) {
    float4 v = *(const float4*)&in[i];
    s16x4 o;
    o[0] = f2bf(v.x); o[1] = f2bf(v.y); o[2] = f2bf(v.z); o[3] = f2bf(v.w);
    *(s16x4*)&out[i] = o;
  }
}

// W (1024x1024 f32, [k][n]) -> Wt (bf16, [n][k])
__global__ void wtrans_k(const float* __restrict__ W, short* __restrict__ Wt) {
  __shared__ float T[64 * 65];
  const int tid = threadIdx.x;
  const int bx = blockIdx.x, by = blockIdx.y; // bx: n-tile, by: k-tile
#pragma unroll
  for (int it = 0; it < 4; ++it) {
    int ci = it * 256 + tid;
    int k = ci >> 4, n4 = (ci & 15) * 4;
    float4 v = *(const float4*)&W[(size_t)(by * 64 + k) * 1024 + bx * 64 + n4];
    T[k * 65 + n4 + 0] = v.x;
    T[k * 65 + n4 + 1] = v.y;
    T[k * 65 + n4 + 2] = v.z;
    T[k * 65 + n4 + 3] = v.w;
  }
  __syncthreads();
#pragma unroll
  for (int it = 0; it < 2; ++it) {
    int co = it * 256 + tid;
    int nn = co >> 3, k8 = (co & 7) * 8;
    bf16x8 o;
#pragma unroll
    for (int jj = 0; jj < 8; ++jj) o[jj] = f2bf(T[(k8 + jj) * 65 + nn]);
    *(bf16x8*)&Wt[(size_t)(bx * 64 + nn) * 1024 + by * 64 + k8] = o;
  }
}

// qscale[d] = (1/sqrt(128))/ln2 * softplus(pds[d])
__global__ void qscale_k(const float* __restrict__ pds, float* __restrict__ qs, double qsb) {
  int d = threadIdx.x;
  double x = (double)pds[d];
  qs[d] = (float)(qsb * log1p(exp(x)));
}

// zero vpadT pad columns: keys [0,127) and [8319,8448)
__global__ void vpadzero_k(short* __restrict__ vpadT) {
  int row = blockIdx.x;                 // (b*8+h)*128 + d   (2048 rows)
  int t = threadIdx.x;                  // 256
  int key = (t < 127) ? t : (8192 + t); // 0..126 and 8319..8447
  vpadT[(size_t)row * 8448 + key] = 0;
}

// ---------------------------------------------------------------------------
// 256x256/8-phase GEMM building blocks.
// LDS half-tile: 128 rows x 8 slots of 16B. Stored swizzled:
//   LDS[r][slot] = G[r][slot ^ (r&7)]   (involution, 16B-granular)
// gl16 dest is lane-linear; the global SOURCE carries the inverse permutation.
// Fragment reads apply the same XOR -> all 32 banks hit uniformly (8 words/bank).

__device__ __forceinline__ void stage_half(short* ldsb, const short* gbase, int tid) {
#pragma unroll
  for (int it = 0; it < 2; ++it) {
    int idx = it * 512 + tid;          // 16B-unit index, 0..1023
    int r = idx >> 3;                  // row 0..127
    int slot = idx & 7;
    int src = (slot ^ (r & 7)) << 3;   // short offset within the row
    gl16((char*)ldsb + idx * 16, gbase + (size_t)r * 1024 + src);
  }
}

__device__ __forceinline__ bf16x8 frag_ld(const short* hb, int row, int ks, int q4) {
  int slot = (ks * 4 + q4) ^ (row & 7);
  return *(const bf16x8*)((const char*)hb + row * 128 + slot * 16);
}

// ---------------------------------------------------------------------------
// R7 fused QKV GEMM: 256x256 tile, BK=64, 8-phase pipeline, fixed swizzle.
__global__ __launch_bounds__(512, 2)
void qkv256_k(const short* __restrict__ A, const short* __restrict__ Bt3,
              short* __restrict__ q_bf, short* __restrict__ kpad,
              short* __restrict__ vpadT,
              const float* __restrict__ qsc, float kscale) {
  // [buf(2)][half(4): A0,A1,B0,B1][128*64 bf16] = 128 KiB
  __shared__ __align__(16) short lds[65536];

  const int tid = threadIdx.x;
  const int lane = tid & 63, wid = tid >> 6;
  const int q4 = lane >> 4, l16 = lane & 15;
  const int wr = wid >> 2, wc = wid & 3;          // 2 M-waves x 4 N-waves

  // XCD-pinned swizzle: 768 blocks = 8 XCD x (8 Mtiles x 12 Ntiles)
  const int id = blockIdx.x;
  const int xcd = id & 7, local = id >> 3;
  const int mm = xcd * 8 + local / 12, nn = local % 12;
  const int m0 = mm * 256, n0 = nn * 256;

  const short* Abase = A + (size_t)m0 * 1024;     // row-major [16384][1024]
  const short* Bbase = Bt3 + (size_t)n0 * 1024;   // 3 weights contiguous, [n][k]

  const f32x4 z4 = {0.f, 0.f, 0.f, 0.f};
  f32x4 acc[8][4];
#pragma unroll
  for (int i = 0; i < 8; ++i)
#pragma unroll
    for (int j = 0; j < 4; ++j) acc[i][j] = z4;

  // ---- prologue: t0 {A0,A1,B0,B1}, t1 {B0,B1}; retire t0, keep t1B in flight
  stage_half(lds + 0 * 32768 + 0 * 8192, Abase, tid);
  stage_half(lds + 0 * 32768 + 1 * 8192, Abase + 128 * 1024, tid);
  stage_half(lds + 0 * 32768 + 2 * 8192, Bbase, tid);
  stage_half(lds + 0 * 32768 + 3 * 8192, Bbase + 128 * 1024, tid);
  stage_half(lds + 1 * 32768 + 2 * 8192, Bbase + 64, tid);
  stage_half(lds + 1 * 32768 + 3 * 8192, Bbase + 128 * 1024 + 64, tid);
  asm volatile("s_waitcnt vmcnt(4)" ::: "memory");
  __builtin_amdgcn_s_barrier();

  for (int kt = 0; kt < 16; ++kt) {
    const int buf = kt & 1;
    const short* Acur = lds + buf * 32768 + wr * 8192;              // this wave's A half
    const short* Bcur = lds + buf * 32768 + (2 + (wc >> 1)) * 8192; // this wave's B half
    const int brow0 = (wc & 1) * 64;

    bf16x8 bfr[4][2];   // B frags held in regs across all 4 phases

    // ---- phase 0: B frags (8 reads) + A quadrant 0 (4 reads); stage (kt+1)A0
    {
#pragma unroll
      for (int j = 0; j < 4; ++j)
#pragma unroll
        for (int ks = 0; ks < 2; ++ks)
          bfr[j][ks] = frag_ld(Bcur, brow0 + j * 16 + l16, ks, q4);
      bf16x8 afr[2][2];
#pragma unroll
      for (int m2 = 0; m2 < 2; ++m2)
#pragma unroll
        for (int ks = 0; ks < 2; ++ks)
          afr[m2][ks] = frag_ld(Acur, m2 * 16 + l16, ks, q4);
      if (kt < 15)
        stage_half(lds + (buf ^ 1) * 32768 + 0 * 8192, Abase + (size_t)(kt + 1) * 64, tid);
      asm volatile("s_waitcnt lgkmcnt(8)" ::: "memory");
      __builtin_amdgcn_s_barrier();
      asm volatile("s_waitcnt lgkmcnt(0)" ::: "memory");
      __builtin_amdgcn_s_setprio(1);
#pragma unroll
      for (int ks = 0; ks < 2; ++ks)
#pragma unroll
        for (int m2 = 0; m2 < 2; ++m2)
#pragma unroll
          for (int j = 0; j < 4; ++j)
            acc[m2][j] = __builtin_amdgcn_mfma_f32_16x16x32_bf16(
                afr[m2][ks], bfr[j][ks], acc[m2][j], 0, 0, 0);
      __builtin_amdgcn_s_setprio(0);
      __builtin_amdgcn_s_barrier();
    }

    // ---- phases 1..3: A quadrant p (4 reads); stage {(kt+1)A1,(kt+2)B0,(kt+2)B1}
#pragma unroll
    for (int p = 1; p < 4; ++p) {
      bf16x8 afr[2][2];
#pragma unroll
      for (int m2 = 0; m2 < 2; ++m2)
#pragma unroll
        for (int ks = 0; ks < 2; ++ks)
          afr[m2][ks] = frag_ld(Acur, (p * 2 + m2) * 16 + l16, ks, q4);
      if (p == 1) {
        if (kt < 15)
          stage_half(lds + (buf ^ 1) * 32768 + 1 * 8192,
                     Abase + 128 * 1024 + (size_t)(kt + 1) * 64, tid);
      } else if (p == 2) {
        if (kt < 14)
          stage_half(lds + buf * 32768 + 2 * 8192, Bbase + (size_t)(kt + 2) * 64, tid);
      } else {
        if (kt < 14)
          stage_half(lds + buf * 32768 + 3 * 8192,
                     Bbase + 128 * 1024 + (size_t)(kt + 2) * 64, tid);
      }
      __builtin_amdgcn_s_barrier();
      asm volatile("s_waitcnt lgkmcnt(0)" ::: "memory");
      __builtin_amdgcn_s_setprio(1);
#pragma unroll
      for (int ks = 0; ks < 2; ++ks)
#pragma unroll
        for (int m2 = 0; m2 < 2; ++m2)
#pragma unroll
          for (int j = 0; j < 4; ++j)
            acc[p * 2 + m2][j] = __builtin_amdgcn_mfma_f32_16x16x32_bf16(
                afr[m2][ks], bfr[j][ks], acc[p * 2 + m2][j], 0, 0, 0);
      __builtin_amdgcn_s_setprio(0);
      if (p == 3) {
        // counted wait, once per K-tile; drain fully only at the pipeline tail
        if (kt < 14) asm volatile("s_waitcnt vmcnt(4)" ::: "memory");
        else         asm volatile("s_waitcnt vmcnt(0)" ::: "memory");
      }
      __builtin_amdgcn_s_barrier();
    }
  }

  // ---- epilogue -----------------------------------------------------------
  const int w = n0 >> 10;          // 0=Q,1=K,2=V
  const int cw = n0 & 1023;        // col offset within this weight
  const int b = m0 >> 13;          // uniform per block
  const int s_base = (m0 & 8191) + wr * 128;

  if (w == 0) {                    // Q -> q_bf[(b*64+n)*8+h][c][d] * qscale[d]
    float qsv[4];
#pragma unroll
    for (int j = 0; j < 4; ++j) qsv[j] = qsc[(cw + wc * 64 + j * 16 + l16) & 127];
#pragma unroll
    for (int m = 0; m < 8; ++m)
#pragma unroll
      for (int j = 0; j < 4; ++j)
#pragma unroll
        for (int rg = 0; rg < 4; ++rg) {
          int s = s_base + m * 16 + q4 * 4 + rg;
          int col = cw + wc * 64 + j * 16 + l16;
          int h = col >> 7, d = col & 127;
          int n = s >> 7, c = s & 127;
          q_bf[((size_t)(((b * 64 + n) * 8 + h) * 128 + c)) * 128 + d] =
              f2bf(acc[m][j][rg] * qsv[j]);
        }
  } else if (w == 1) {             // K -> kpad[b][h][127+s][d] * kscale
#pragma unroll
    for (int m = 0; m < 8; ++m)
#pragma unroll
      for (int j = 0; j < 4; ++j)
#pragma unroll
        for (int rg = 0; rg < 4; ++rg) {
          int s = s_base + m * 16 + q4 * 4 + rg;
          int col = cw + wc * 64 + j * 16 + l16;
          int h = col >> 7, d = col & 127;
          kpad[((size_t)(b * 8 + h) * 8448 + 127 + s) * 128 + d] =
              f2bf(acc[m][j][rg] * kscale);
        }
  } else {                         // V -> vpadT[(b*8+h)*128+d][127+s], LDS transpose
    short* T = lds;                // reuse main-loop LDS (all staged data consumed)
#pragma unroll
    for (int hh = 0; hh < 2; ++hh) {
      __syncthreads();
      if ((wc >> 1) == hh) {
#pragma unroll
        for (int m = 0; m < 8; ++m)
#pragma unroll
          for (int j = 0; j < 4; ++j)
#pragma unroll
            for (int rg = 0; rg < 4; ++rg) {
              int sl = wr * 128 + m * 16 + q4 * 4 + rg;  // 0..255
              int dl = (wc & 1) * 64 + j * 16 + l16;     // 0..127
              T[dl * 264 + sl] = f2bf(acc[m][j][rg]);
            }
      }
      __syncthreads();
      const int h = (cw >> 7) + hh;
#pragma unroll
      for (int it = 0; it < 8; ++it) {
        int co = it * 512 + tid;
        int dd = co >> 5, s8 = (co & 31) * 8;
        *(bf16x8*)&vpadT[((size_t)(b * 8 + h) * 128 + dd) * 8448 + 127 + (m0 & 8191) + s8] =
            *(const bf16x8*)&T[dd * 264 + s8];
      }
    }
  }
}

// ---------------------------------------------------------------------------
// R7 post GEMM on the 256x256/8-phase template. M=16384 N=1024 K=1024,
// grid 256 = 8 XCD x (8 Mtiles x 4 Ntiles) = 1 block/CU. f32 output.
__global__ __launch_bounds__(512, 2)
void post256_k(const short* __restrict__ A, const short* __restrict__ Bt,
               float* __restrict__ outf) {
  __shared__ __align__(16) short lds[65536];

  const int tid = threadIdx.x;
  const int lane = tid & 63, wid = tid >> 6;
  const int q4 = lane >> 4, l16 = lane & 15;
  const int wr = wid >> 2, wc = wid & 3;

  const int id = blockIdx.x;
  const int xcd = id & 7, local = id >> 3;      // local in [0,32)
  const int mm = xcd * 8 + (local >> 2), nn = local & 3;
  const int m0 = mm * 256, n0 = nn * 256;

  const short* Abase = A + (size_t)m0 * 1024;
  const short* Bbase = Bt + (size_t)n0 * 1024;

  const f32x4 z4 = {0.f, 0.f, 0.f, 0.f};
  f32x4 acc[8][4];
#pragma unroll
  for (int i = 0; i < 8; ++i)
#pragma unroll
    for (int j = 0; j < 4; ++j) acc[i][j] = z4;

  stage_half(lds + 0 * 32768 + 0 * 8192, Abase, tid);
  stage_half(lds + 0 * 32768 + 1 * 8192, Abase + 128 * 1024, tid);
  stage_half(lds + 0 * 32768 + 2 * 8192, Bbase, tid);
  stage_half(lds + 0 * 32768 + 3 * 8192, Bbase + 128 * 1024, tid);
  stage_half(lds + 1 * 32768 + 2 * 8192, Bbase + 64, tid);
  stage_half(lds + 1 * 32768 + 3 * 8192, Bbase + 128 * 1024 + 64, tid);
  asm volatile("s_waitcnt vmcnt(4)" ::: "memory");
  __builtin_amdgcn_s_barrier();

  for (int kt = 0; kt < 16; ++kt) {
    const int buf = kt & 1;
    const short* Acur = lds + buf * 32768 + wr * 8192;
    const short* Bcur = lds + buf * 32768 + (2 + (wc >> 1)) * 8192;
    const int brow0 = (wc & 1) * 64;

    bf16x8 bfr[4][2];

    {
#pragma unroll
      for (int j = 0; j < 4; ++j)
#pragma unroll
        for (int ks = 0; ks < 2; ++ks)
          bfr[j][ks] = frag_ld(Bcur, brow0 + j * 16 + l16, ks, q4);
      bf16x8 afr[2][2];
#pragma unroll
      for (int m2 = 0; m2 < 2; ++m2)
#pragma unroll
        for (int ks = 0; ks < 2; ++ks)
          afr[m2][ks] = frag_ld(Acur, m2 * 16 + l16, ks, q4);
      if (kt < 15)
        stage_half(lds + (buf ^ 1) * 32768 + 0 * 8192, Abase + (size_t)(kt + 1) * 64, tid);
      asm volatile("s_waitcnt lgkmcnt(8)" ::: "memory");
      __builtin_amdgcn_s_barrier();
      asm volatile("s_waitcnt lgkmcnt(0)" ::: "memory");
      __builtin_amdgcn_s_setprio(1);
#pragma unroll
      for (int ks = 0; ks < 2; ++ks)
#pragma unroll
        for (int m2 = 0; m2 < 2; ++m2)
#pragma unroll
          for (int j = 0; j < 4; ++j)
            acc[m2][j] = __builtin_amdgcn_mfma_f32_16x16x32_bf16(
                afr[m2][ks], bfr[j][ks], acc[m2][j], 0, 0, 0);
      __builtin_amdgcn_s_setprio(0);
      __builtin_amdgcn_s_barrier();
    }

#pragma unroll
    for (int p = 1; p < 4; ++p) {
      bf16x8 afr[2][2];
#pragma unroll
      for (int m2 = 0; m2 < 2; ++m2)
#pragma unroll
        for (int ks = 0; ks < 2; ++ks)
          afr[m2][ks] = frag_ld(Acur, (p * 2 + m2) * 16 + l16, ks, q4);
      if (p == 1) {
        if (kt < 15)
          stage_half(lds + (buf ^ 1) * 32768 + 1 * 8192,
                     Abase + 128 * 1024 + (size_t)(kt + 1) * 64, tid);
      } else if (p == 2) {
        if (kt < 14)
          stage_half(lds + buf * 32768 + 2 * 8192, Bbase + (size_t)(kt + 2) * 64, tid);
      } else {
        if (kt < 14)
          stage_half(lds + buf * 32768 + 3 * 8192,
                     Bbase + 128 * 1024 + (size_t)(kt + 2) * 64, tid);
      }
      __builtin_amdgcn_s_barrier();
      asm volatile("s_waitcnt lgkmcnt(0)" ::: "memory");
      __builtin_amdgcn_s_setprio(1);
#pragma unroll
      for (int ks = 0; ks < 2; ++ks)
#pragma unroll
        for (int m2 = 0; m2 < 2; ++m2)
#pragma unroll
          for (int j = 0; j < 4; ++j)
            acc[p * 2 + m2][j] = __builtin_amdgcn_mfma_f32_16x16x32_bf16(
                afr[m2][ks], bfr[j][ks], acc[p * 2 + m2][j], 0, 0, 0);
      __builtin_amdgcn_s_setprio(0);
      if (p == 3) {
        if (kt < 14) asm volatile("s_waitcnt vmcnt(4)" ::: "memory");
        else         asm volatile("s_waitcnt vmcnt(0)" ::: "memory");
      }
      __builtin_amdgcn_s_barrier();
    }
  }

#pragma unroll
  for (int m = 0; m < 8; ++m)
#pragma unroll
    for (int j = 0; j < 4; ++j)
#pragma unroll
      for (int rg = 0; rg < 4; ++rg) {
        const int row = m0 + wr * 128 + m * 16 + q4 * 4 + rg;
        const int col = n0 + wc * 64 + j * 16 + l16;
        outf[(size_t)row * 1024 + col] = acc[m][j][rg];
      }
}

// ---------------------------------------------------------------------------
// REL GEMM: C = pos_bf(384x1024) @ Wrel_t^T -> relk[h][p][d]. grid (3,8).
__global__ __launch_bounds__(256, 2)
void rel_gemm_k(const short* __restrict__ A, const short* __restrict__ Bt,
                short* __restrict__ relk) {
  __shared__ __align__(16) short As[128 * 32];
  __shared__ __align__(16) short Bs[128 * 32];

  const int tid = threadIdx.x;
  const int lane = tid & 63, wid = tid >> 6;
  const int q4 = lane >> 4, l16 = lane & 15;
  const int wr = wid >> 1, wc = wid & 1;
  const int m0 = blockIdx.x * 128, n0 = blockIdx.y * 128;

  const f32x4 z4 = {0.f, 0.f, 0.f, 0.f};
  f32x4 acc[4][4];
#pragma unroll
  for (int i = 0; i < 4; ++i)
#pragma unroll
    for (int j = 0; j < 4; ++j) acc[i][j] = z4;

  const int r0 = tid >> 2, s0_ = (tid & 3) * 8;
  for (int kk = 0; kk < 1024; kk += 32) {
    __syncthreads();
    gl16(&As[tid * 8],         A  + (size_t)(m0 + r0) * 1024 + kk + s0_);
    gl16(&Bs[tid * 8],         Bt + (size_t)(n0 + r0) * 1024 + kk + s0_);
    gl16(&As[(256 + tid) * 8], A  + (size_t)(m0 + 64 + r0) * 1024 + kk + s0_);
    gl16(&Bs[(256 + tid) * 8], Bt + (size_t)(n0 + 64 + r0) * 1024 + kk + s0_);
    __syncthreads();
    bf16x8 af[4], bfv[4];
#pragma unroll
    for (int i = 0; i < 4; ++i)
      af[i] = *(const bf16x8*)&As[(wr * 64 + i * 16 + l16) * 32 + q4 * 8];
#pragma unroll
    for (int j = 0; j < 4; ++j)
      bfv[j] = *(const bf16x8*)&Bs[(wc * 64 + j * 16 + l16) * 32 + q4 * 8];
#pragma unroll
    for (int i = 0; i < 4; ++i)
#pragma unroll
      for (int j = 0; j < 4; ++j)
        acc[i][j] = __builtin_amdgcn_mfma_f32_16x16x32_bf16(af[i], bfv[j], acc[i][j], 0, 0, 0);
  }

#pragma unroll
  for (int i = 0; i < 4; ++i)
#pragma unroll
    for (int j = 0; j < 4; ++j)
#pragma unroll
      for (int rg = 0; rg < 4; ++rg) {
        const int row = m0 + wr * 64 + i * 16 + q4 * 4 + rg;
        const int col = n0 + wc * 64 + j * 16 + l16;
        int h = col >> 7, d = col & 127;
        relk[(size_t)(h * 384 + row) * 128 + d] = f2bf(acc[i][j][rg]);
      }
}

// ---------------------------------------------------------------------------
// bdo = q_tile(128x128) @ relk[h](384x128)^T, rel-shift applied in epilogue,
// stored in MFMA-fragment order for attn_k (unchanged from R4).
__global__ __launch_bounds__(256, 2)
void bd_gemm_k(const short* __restrict__ qb_b, const short* __restrict__ relk,
               short* __restrict__ bds) {
  __shared__ __align__(16) short As[128 * 32];
  __shared__ __align__(16) short Bs[128 * 32];
  const int tid = threadIdx.x;
  const int lane = tid & 63, wid = tid >> 6;
  const int q4 = lane >> 4, l16 = lane & 15;
  const int wr = wid >> 1, wc = wid & 1;
  const int p0 = blockIdx.x * 128;
  const int nh = blockIdx.y;          // n*8 + h  (within b)
  const int h = nh & 7;
  const short* A = qb_b + (size_t)nh * 16384;
  const short* Bt = relk + (size_t)h * (384 * 128);
  short* bdo = bds + (size_t)nh * 49152;

  const f32x4 z4 = {0.f, 0.f, 0.f, 0.f};
  f32x4 acc[4][4];
#pragma unroll
  for (int i = 0; i < 4; ++i)
#pragma unroll
    for (int j = 0; j < 4; ++j) acc[i][j] = z4;

  const int r0 = tid >> 2, s0_ = (tid & 3) * 8;
  for (int kk = 0; kk < 128; kk += 32) {
    __syncthreads();
    gl16(&As[tid * 8],         A  + (size_t)r0 * 128 + kk + s0_);
    gl16(&Bs[tid * 8],         Bt + (size_t)(p0 + r0) * 128 + kk + s0_);
    gl16(&As[(256 + tid) * 8], A  + (size_t)(64 + r0) * 128 + kk + s0_);
    gl16(&Bs[(256 + tid) * 8], Bt + (size_t)(p0 + 64 + r0) * 128 + kk + s0_);
    __syncthreads();
    bf16x8 af[4], bfv[4];
#pragma unroll
    for (int i = 0; i < 4; ++i)
      af[i] = *(const bf16x8*)&As[(wr * 64 + i * 16 + l16) * 32 + q4 * 8];
#pragma unroll
    for (int j = 0; j < 4; ++j)
      bfv[j] = *(const bf16x8*)&Bs[(wc * 64 + j * 16 + l16) * 32 + q4 * 8];
#pragma unroll
    for (int i = 0; i < 4; ++i)
#pragma unroll
      for (int j = 0; j < 4; ++j)
        acc[i][j] = __builtin_amdgcn_mfma_f32_16x16x32_bf16(af[i], bfv[j], acc[i][j], 0, 0, 0);
  }

  // rel-shift: (r,p) -> (c,k): flat r*384+p == c*383+k, drop c >= 128
#pragma unroll
  for (int i = 0; i < 4; ++i)
#pragma unroll
    for (int j = 0; j < 4; ++j)
#pragma unroll
      for (int rg = 0; rg < 4; ++rg) {
        int r = wr * 64 + i * 16 + q4 * 4 + rg;
        int p = p0 + wc * 64 + j * 16 + l16;
        int t = r + p;
        int c = (t < 383) ? r : (r + 1);
        int k = (t < 383) ? t : (t - 383);
        if (c < 128) {
          int tt = k >> 7, jj = (k >> 4) & 7, ll = k & 15;
          int wa = c >> 5, ia = (c >> 4) & 1, qa = (c >> 2) & 3, ra = c & 3;
          bdo[((((size_t)tt * 8 + jj) * 256) + wa * 64 + qa * 16 + ll) * 8 + ia * 4 + ra] =
              f2bf(acc[i][j][rg]);
        }
      }
}

// ---------------------------------------------------------------------------
// fused local attention, 64-query-row blocks: one WG per (n,h,qh) for fixed b.
// grid 1024. LDS 50.2 KB -> 3 blocks/CU.
__global__ __launch_bounds__(256, 3)
void attn_k(const short* __restrict__ qb_b, const short* __restrict__ kpad,
            const short* __restrict__ vpadT, const short* __restrict__ bds,
            short* __restrict__ attnout, int b) {
  __shared__ __align__(16) short Ks[4 * 128 * 32]; // slabs [dc][row][32], reused Q->K->V
  __shared__ __align__(16) short Ps[64 * 136];     // 64-row P tile, padded stride

  const int tid = threadIdx.x;
  const int lane = tid & 63, wid = tid >> 6;
  const int q4 = lane >> 4, l16 = lane & 15;
  const int bx = blockIdx.x;          // (n*8 + h)*2 + qh
  const int qh = bx & 1, nh = bx >> 1;
  const int n = nh >> 3, h = nh & 7;

  const short* qtile = qb_b + (size_t)nh * 16384 + qh * 64 * 128;
  const short* kbase = kpad + ((size_t)(b * 8 + h) * 8448 + n * 128) * 128;
  const short* vtb = vpadT + (size_t)(b * 8 + h) * 128 * 8448 + n * 128;
  const short* bdb = bds + (size_t)nh * 49152;

  // stage this half's Q (64x128) into Ks, pull fragments to registers
#pragma unroll
  for (int it = 0; it < 4; ++it) {
    int ci = it * 256 + tid;                     // [0,1024)
    int dc = ci >> 8, rr = (ci >> 2) & 63, sub = (ci & 3) * 8;
    gl16(&Ks[ci * 8], qtile + rr * 128 + dc * 32 + sub);
  }
  __syncthreads();
  bf16x8 qf[4];
#pragma unroll
  for (int dc = 0; dc < 4; ++dc)
    qf[dc] = *(const bf16x8*)&Ks[dc * 2048 + (wid * 16 + l16) * 32 + q4 * 8];

  const f32x4 z4 = {0.f, 0.f, 0.f, 0.f};
  f32x4 acco[8];
#pragma unroll
  for (int j = 0; j < 8; ++j) acco[j] = z4;
  float rsum[4] = {};

  for (int t = 0; t < 3; ++t) {
    __syncthreads();  // (A) Ks/Ps free
#pragma unroll
    for (int it = 0; it < 8; ++it) {  // stage K tile (full 128 keys)
      int ci = it * 256 + tid;
      int dc = ci >> 9, rr = (ci >> 2) & 127, sub = (ci & 3) * 8;
      gl16(&Ks[ci * 8], kbase + (size_t)(t * 128 + rr) * 128 + dc * 32 + sub);
    }

    // bd fragment loads (8B per lane, this wave's ia-half only)
    s16x4 bdv[8];
#pragma unroll
    for (int j = 0; j < 8; ++j)
      bdv[j] = *(const s16x4*)&bdb[((((size_t)t * 8 + j) * 256) +
                 (qh * 2 + (wid >> 1)) * 64 + q4 * 16 + l16) * 8 + (wid & 1) * 4];

    __syncthreads();  // (B) K ready

    // S = Q @ K^T  (16 rows per wave)
    f32x4 accs[8];
#pragma unroll
    for (int j = 0; j < 8; ++j) accs[j] = z4;
#pragma unroll
    for (int dc = 0; dc < 4; ++dc) {
      bf16x8 kf[8];
#pragma unroll
      for (int j = 0; j < 8; ++j)
        kf[j] = *(const bf16x8*)&Ks[dc * 4096 + (j * 16 + l16) * 32 + q4 * 8];
#pragma unroll
      for (int j = 0; j < 8; ++j)
        accs[j] = __builtin_amdgcn_mfma_f32_16x16x32_bf16(qf[dc], kf[j], accs[j], 0, 0, 0);
    }

    // logits: s = ac + bd;  w = exp2(-100*log2e / (exp2(s*2*log2e/50) + 1))
#pragma unroll
    for (int j = 0; j < 8; ++j) {
      const int kg = t * 128 + j * 16 + l16;
#pragma unroll
      for (int rg = 0; rg < 4; ++rg) {
        float sv = accs[j][rg] + bf2f((unsigned short)bdv[j][rg]);
        float tt = exp2f(sv * 0.057707801635558534f);
        float wgt = exp2f(-144.26950408889634f * __fdividef(1.0f, tt + 1.0f));
        wgt = (kg < 383) ? wgt : 0.0f;
        accs[j][rg] = wgt;
        rsum[rg] += wgt;
      }
    }
    __syncthreads();  // (C) all waves done reading Ks (K tile)

    // stage V^T tile into Ks slabs [kc][d][32keys]; write P to Ps
#pragma unroll
    for (int it = 0; it < 8; ++it) {
      int ci = it * 256 + tid;
      int kc = ci >> 9, dd = (ci >> 2) & 127, sub = (ci & 3) * 8;
      gl16(&Ks[ci * 8], vtb + (size_t)dd * 8448 + t * 128 + kc * 32 + sub);
    }
#pragma unroll
    for (int j = 0; j < 8; ++j)
#pragma unroll
      for (int rg = 0; rg < 4; ++rg) {
        int c = wid * 16 + q4 * 4 + rg;
        int kl = j * 16 + l16;
        Ps[c * 136 + kl] = f2bf(accs[j][rg]);
      }
    __syncthreads();  // (D) V + P ready

    // PV over kc = 0..3
#pragma unroll
    for (int kc = 0; kc < 4; ++kc) {
      bf16x8 pf, vf[8];
      pf = *(const bf16x8*)&Ps[(wid * 16 + l16) * 136 + kc * 32 + q4 * 8];
#pragma unroll
      for (int j = 0; j < 8; ++j)
        vf[j] = *(const bf16x8*)&Ks[kc * 4096 + (j * 16 + l16) * 32 + q4 * 8];
#pragma unroll
      for (int j = 0; j < 8; ++j)
        acco[j] = __builtin_amdgcn_mfma_f32_16x16x32_bf16(pf, vf[j], acco[j], 0, 0, 0);
    }
  }

  // row-sum butterfly over the 16-lane group (cols), normalize, write bf16
  float rinv[4];
#pragma unroll
  for (int rg = 0; rg < 4; ++rg) {
    float rs = rsum[rg];
    rs += __shfl_xor(rs, 1);
    rs += __shfl_xor(rs, 2);
    rs += __shfl_xor(rs, 4);
    rs += __shfl_xor(rs, 8);
    rinv[rg] = __fdividef(1.0f, rs);
  }
#pragma unroll
  for (int j = 0; j < 8; ++j)
#pragma unroll
    for (int rg = 0; rg < 4; ++rg) {
      int srow = n * 128 + qh * 64 + wid * 16 + q4 * 4 + rg;
      int col = h * 128 + j * 16 + l16;
      attnout[((size_t)b * 8192 + srow) * 1024 + col] = f2bf(acco[j][rg] * rinv[rg]);
    }
}

// ---------------------------------------------------------------------------
extern "C" void kernel_launch(void* const* d_in, const int* in_sizes, int n_in,
                              void* d_out, int out_size, void* d_ws, size_t ws_size,
                              hipStream_t stream) {
  (void)in_sizes; (void)n_in; (void)out_size; (void)ws_size;
  const float* hs    = (const float*)d_in[0];
  const float* pemb  = (const float*)d_in[1];
  const float* Wq    = (const float*)d_in[2];
  const float* Wk    = (const float*)d_in[3];
  const float* Wv    = (const float*)d_in[4];
  const float* Wrel  = (const float*)d_in[5];
  const float* Wpost = (const float*)d_in[6];
  const float* pds   = (const float*)d_in[7];
  float* out = (float*)d_out;

  char* w = (char*)d_ws;
  auto alloc = [&](size_t bytes) -> char* {
    char* p = w; w += (bytes + 255) & ~(size_t)255; return p;
  };
  short* hs_bf   = (short*)alloc((size_t)16384 * 1024 * 2); // 33.5 MB (attnout aliases later)
  short* pos_bf  = (short*)alloc((size_t)384 * 1024 * 2);
  short* Wq_t    = (short*)alloc((size_t)1024 * 1024 * 2);  // Wq_t/Wk_t/Wv_t contiguous = Bt3
  short* Wk_t    = (short*)alloc((size_t)1024 * 1024 * 2);
  short* Wv_t    = (short*)alloc((size_t)1024 * 1024 * 2);
  short* Wrel_t  = (short*)alloc((size_t)1024 * 1024 * 2);
  short* Wpost_t = (short*)alloc((size_t)1024 * 1024 * 2);
  float* qsc     = (float*)alloc(512);
  short* q_bf    = (short*)alloc((size_t)2 * 64 * 8 * 128 * 128 * 2); // 33.5 MB
  short* kpad    = (short*)alloc((size_t)2 * 8 * 8448 * 128 * 2);     // 34.6 MB
  short* vpadT   = (short*)alloc((size_t)2 * 8 * 128 * 8448 * 2);     // 34.6 MB
  short* relk    = (short*)alloc((size_t)8 * 384 * 128 * 2);
  short* bds     = (short*)alloc((size_t)64 * 8 * 128 * 384 * 2);     // 50.3 MB, per-b (reused)
  short* attnout = hs_bf;  // hs_bf dead after QKV projection; attn starts after
  // total ~199 MB (< 232 MB known-good)

  const float kscale = (float)(log1p(exp(1.0)) / log(2.0));
  const double qsb = (1.0 / sqrt(128.0)) / log(2.0);

  cvt_bf16_k<<<16384, 256, 0, stream>>>(hs, hs_bf, 16384 * 1024);
  cvt_bf16_k<<<384, 256, 0, stream>>>(pemb, pos_bf, 384 * 1024);
  dim3 tg(16, 16);
  wtrans_k<<<tg, 256, 0, stream>>>(Wq, Wq_t);
  wtrans_k<<<tg, 256, 0, stream>>>(Wk, Wk_t);
  wtrans_k<<<tg, 256, 0, stream>>>(Wv, Wv_t);
  wtrans_k<<<tg, 256, 0, stream>>>(Wrel, Wrel_t);
  wtrans_k<<<tg, 256, 0, stream>>>(Wpost, Wpost_t);
  qscale_k<<<1, 128, 0, stream>>>(pds, qsc, qsb);
  hipMemsetAsync(kpad, 0, (size_t)2 * 8 * 8448 * 128 * 2, stream);
  vpadzero_k<<<2048, 256, 0, stream>>>(vpadT);

  qkv256_k<<<768, 512, 0, stream>>>(hs_bf, Wq_t, q_bf, kpad, vpadT, qsc, kscale);
  rel_gemm_k<<<dim3(3, 8), 256, 0, stream>>>(pos_bf, Wrel_t, relk);

  for (int b = 0; b < 2; ++b) {
    const short* qb_b = q_bf + (size_t)b * 64 * 8 * 128 * 128;
    bd_gemm_k<<<dim3(3, 512), 256, 0, stream>>>(qb_b, relk, bds);
    attn_k<<<1024, 256, 0, stream>>>(qb_b, kpad, vpadT, bds, attnout, b);
  }

  post256_k<<<256, 512, 0, stream>>>(attnout, Wpost_t, out);
}